// Round 4
// baseline (138.002 us; speedup 1.0000x reference)
//
#include <hip/hip_runtime.h>
#include <math.h>

#define NB   16
#define EMB  128

typedef __bf16 bf16x8 __attribute__((ext_vector_type(8)));
typedef __bf16 bf16x4 __attribute__((ext_vector_type(4)));
typedef float  f32x4  __attribute__((ext_vector_type(4)));
typedef int    i32x4  __attribute__((ext_vector_type(4)));

// ---------------------------------------------------------------------------
// Prep: pack [Ws0; Wn0] (K=256 x N=128) as bf16 MFMA B-fragments.
// frag (s,nt) at pack[((s*8+nt)*64 + lane)*8 + j] holds
// W[k = s*32 + (lane>>4)*8 + j][col = nt*16 + (lane&15)].
// ---------------------------------------------------------------------------
__global__ __launch_bounds__(256) void pack_w_kernel(
    const float* __restrict__ Ws0, const float* __restrict__ Wn0,
    __bf16* __restrict__ pack)
{
    int idx = blockIdx.x * 256 + threadIdx.x;   // (s<<9)|(nt<<6)|lane
    if (idx >= 4096) return;
    int l  = idx & 63;
    int nt = (idx >> 6) & 7;
    int s  = idx >> 9;
    int col = nt * 16 + (l & 15);
    int k0  = s * 32 + (l >> 4) * 8;
    bf16x8 v;
    #pragma unroll
    for (int j = 0; j < 8; ++j) {
        int k = k0 + j;
        float wv = (k < 128) ? Ws0[k * EMB + col] : Wn0[(k - 128) * EMB + col];
        v[j] = (__bf16)wv;
    }
    *(bf16x8*)(pack + idx * 8) = v;
}

// ---------------------------------------------------------------------------
// Main fused kernel: one block (256 thr = 4 waves) per batch element.
// waves_per_eu(4,4): pins the register-allocator budget at 128 VGPR so the
// 16+ gather loads of each phase-D round stay in flight (at the default
// 8-wave target the compiler serialized them at VGPR_Count=52).
// ---------------------------------------------------------------------------
__global__ __launch_bounds__(256)
__attribute__((amdgpu_waves_per_eu(4, 4)))
void gnn_kernel(
    const int* __restrict__ node, const int* __restrict__ relation,
    const int* __restrict__ adj_node, const int* __restrict__ adj_rela,
    const int* __restrict__ node_type, const float* __restrict__ node_emb,
    const float* __restrict__ rela_emb, const float* __restrict__ type_w,
    const float* __restrict__ Ws1, const float* __restrict__ Wn1,
    const __bf16* __restrict__ packW0,
    float* __restrict__ out)
{
    // X: row r in [0,17), col c in [0,256): byte = (r*512 + c*2) ^ ((r&7)<<4)
    __shared__ __align__(16) unsigned char Xb[17 * 512];
    __shared__ __align__(16) float sw01[16][16];
    __shared__ __align__(16) int   se2[16][16];
    __shared__ __align__(16) float relv[EMB];
    __shared__ __align__(16) f32x4 red4[8][32];   // D: agg0 partials; H: out partials
    __shared__ __align__(16) float y0[EMB];       // v0
    __shared__ __align__(16) float y1[EMB];       // aggf
    __shared__ float sw00[16];
    __shared__ float srsim[16];
    __shared__ float sdij[16], sdrr[16];
    __shared__ int   se1[16], sr1[16], st1[16];

    const int t   = threadIdx.x;
    const int b   = blockIdx.x;
    const int nb0 = node[b];
    const int rel = relation[b];

    // ---------- Phase A ----------
    if (t < 16) {
        int e1 = adj_node[nb0 * NB + t];
        se1[t] = e1;
        sr1[t] = adj_rela[nb0 * NB + t];
        st1[t] = node_type[e1];
    }
    if (t < EMB) relv[t] = rela_emb[rel * EMB + t];
    {
        int r = t >> 4, c = t & 15;
        float dij = 0.f, drr = 0.f;
        #pragma unroll
        for (int dd = 0; dd < 8; ++dd) {
            int d = dd * 16 + c;
            float a  = rela_emb[rel * EMB + d];
            float bb = rela_emb[r * EMB + d];
            dij = fmaf(a, bb, dij);
            drr = fmaf(bb, bb, drr);
        }
        #pragma unroll
        for (int off = 8; off >= 1; off >>= 1) {
            dij += __shfl_xor(dij, off);
            drr += __shfl_xor(drr, off);
        }
        if (c == 0) { sdij[r] = dij; sdrr[r] = drr; }
    }
    __syncthreads();

    // ---------- Phase B ----------
    if (t < 16) {
        float nrel = fmaxf(sqrtf(sdrr[rel]), 1e-8f);
        float nr   = fmaxf(sqrtf(sdrr[t]),   1e-8f);
        srsim[t] = fabsf(sdij[t]) / (nr * nrel);
    }
    __syncthreads();

    // ---------- Phase C: scores + softmax ----------
    {
        int k = t >> 4, j = t & 15;
        int e1k = se1[k];
        int e2  = adj_node[e1k * NB + j];
        int r2  = adj_rela[e1k * NB + j];
        int t2  = node_type[e2];
        se2[k][j] = e2;
        float s = srsim[r2] * type_w[st1[k] * 4 + t2];
        float m = s;
        #pragma unroll
        for (int off = 8; off >= 1; off >>= 1) m = fmaxf(m, __shfl_xor(m, off));
        float ex = __expf(s - m);
        float sum = ex;
        #pragma unroll
        for (int off = 8; off >= 1; off >>= 1) sum += __shfl_xor(sum, off);
        sw01[k][j] = ex / sum;
    }
    {
        int t0type = node_type[nb0];
        if (t < 16) {
            float s = srsim[sr1[t]] * type_w[t0type * 4 + st1[t]];
            float m = s;
            #pragma unroll
            for (int off = 8; off >= 1; off >>= 1) m = fmaxf(m, __shfl_xor(m, off));
            float ex = __expf(s - m);
            float sum = ex;
            #pragma unroll
            for (int off = 8; off >= 1; off >>= 1) sum += __shfl_xor(sum, off);
            sw00[t] = ex / sum;
        }
    }
    __syncthreads();

    // ---------- Phase D: float4 gather -> X rows (max MLP) ----------
    {
        const int q = t & 31;     // col quad: cols 4q..4q+3
        const int g = t >> 5;     // 0..7
        const int kA = g, kB = g + 8;
        const int swzA = (kA & 7) << 4, swzB = swzA;
        const float* __restrict__ nbq = node_emb + q * 4;
        const f32x4 rv4 = *(const f32x4*)&relv[q * 4];

        // round-A indices + weights (ds_read_b128 x8)
        i32x4 iA0 = *(const i32x4*)&se2[kA][0];
        i32x4 iA1 = *(const i32x4*)&se2[kA][4];
        i32x4 iA2 = *(const i32x4*)&se2[kA][8];
        i32x4 iA3 = *(const i32x4*)&se2[kA][12];
        f32x4 wA0 = *(const f32x4*)&sw01[kA][0];
        f32x4 wA1 = *(const f32x4*)&sw01[kA][4];
        f32x4 wA2 = *(const f32x4*)&sw01[kA][8];
        f32x4 wA3 = *(const f32x4*)&sw01[kA][12];

        // issue both self rows + hop0 row + all 16 round-A loads
        const f32x4 svA = *(const f32x4*)(nbq + (se1[kA] << 7));
        const f32x4 svB = *(const f32x4*)(nbq + (se1[kB] << 7));
        f32x4 ev0 = {0.f, 0.f, 0.f, 0.f};
        if (g == 0) ev0 = *(const f32x4*)(node_emb + (nb0 << 7) + q * 4);

        f32x4 a0  = *(const f32x4*)(nbq + (iA0[0] << 7));
        f32x4 a1  = *(const f32x4*)(nbq + (iA0[1] << 7));
        f32x4 a2  = *(const f32x4*)(nbq + (iA0[2] << 7));
        f32x4 a3  = *(const f32x4*)(nbq + (iA0[3] << 7));
        f32x4 a4  = *(const f32x4*)(nbq + (iA1[0] << 7));
        f32x4 a5  = *(const f32x4*)(nbq + (iA1[1] << 7));
        f32x4 a6  = *(const f32x4*)(nbq + (iA1[2] << 7));
        f32x4 a7  = *(const f32x4*)(nbq + (iA1[3] << 7));
        f32x4 a8  = *(const f32x4*)(nbq + (iA2[0] << 7));
        f32x4 a9  = *(const f32x4*)(nbq + (iA2[1] << 7));
        f32x4 a10 = *(const f32x4*)(nbq + (iA2[2] << 7));
        f32x4 a11 = *(const f32x4*)(nbq + (iA2[3] << 7));
        f32x4 a12 = *(const f32x4*)(nbq + (iA3[0] << 7));
        f32x4 a13 = *(const f32x4*)(nbq + (iA3[1] << 7));
        f32x4 a14 = *(const f32x4*)(nbq + (iA3[2] << 7));
        f32x4 a15 = *(const f32x4*)(nbq + (iA3[3] << 7));

        // round-B indices + weights (overlap with round-A flight time)
        i32x4 iB0 = *(const i32x4*)&se2[kB][0];
        i32x4 iB1 = *(const i32x4*)&se2[kB][4];
        i32x4 iB2 = *(const i32x4*)&se2[kB][8];
        i32x4 iB3 = *(const i32x4*)&se2[kB][12];
        f32x4 wB0 = *(const f32x4*)&sw01[kB][0];
        f32x4 wB1 = *(const f32x4*)&sw01[kB][4];
        f32x4 wB2 = *(const f32x4*)&sw01[kB][8];
        f32x4 wB3 = *(const f32x4*)&sw01[kB][12];

        // self-row products / stores
        f32x4 pagg = sw00[kA] * svA;
        pagg += sw00[kB] * svB;
        bf16x4 xsA, xsB;
        #pragma unroll
        for (int c = 0; c < 4; ++c) {
            xsA[c] = (__bf16)(svA[c] * rv4[c]);
            xsB[c] = (__bf16)(svB[c] * rv4[c]);
        }
        *(bf16x4*)(Xb + ((kA * 512 + q * 8) ^ swzA)) = xsA;
        *(bf16x4*)(Xb + ((kB * 512 + q * 8) ^ swzB)) = xsB;
        if (g == 0) {
            bf16x4 h0s;
            #pragma unroll
            for (int c = 0; c < 4; ++c) h0s[c] = (__bf16)(ev0[c] * rv4[c]);
            *(bf16x4*)(Xb + 16 * 512 + q * 8) = h0s;   // row16 self (no swizzle)
        }

        // round-A combine (pairwise tree)
        {
            f32x4 s01 = wA0[0] * a0;  s01 += wA0[1] * a1;
            f32x4 s23 = wA0[2] * a2;  s23 += wA0[3] * a3;
            f32x4 s45 = wA1[0] * a4;  s45 += wA1[1] * a5;
            f32x4 s67 = wA1[2] * a6;  s67 += wA1[3] * a7;
            f32x4 s89 = wA2[0] * a8;  s89 += wA2[1] * a9;
            f32x4 sab = wA2[2] * a10; sab += wA2[3] * a11;
            f32x4 scd = wA3[0] * a12; scd += wA3[1] * a13;
            f32x4 sef = wA3[2] * a14; sef += wA3[3] * a15;
            s01 += s23; s45 += s67; s89 += sab; scd += sef;
            s01 += s45; s89 += scd;
            f32x4 acc = s01 + s89;
            bf16x4 xa;
            #pragma unroll
            for (int c = 0; c < 4; ++c) xa[c] = (__bf16)(acc[c] * rv4[c]);
            *(bf16x4*)(Xb + ((kA * 512 + 256 + q * 8) ^ swzA)) = xa;
        }

        // round-B loads + combine
        {
            f32x4 b0  = *(const f32x4*)(nbq + (iB0[0] << 7));
            f32x4 b1  = *(const f32x4*)(nbq + (iB0[1] << 7));
            f32x4 b2  = *(const f32x4*)(nbq + (iB0[2] << 7));
            f32x4 b3  = *(const f32x4*)(nbq + (iB0[3] << 7));
            f32x4 b4  = *(const f32x4*)(nbq + (iB1[0] << 7));
            f32x4 b5  = *(const f32x4*)(nbq + (iB1[1] << 7));
            f32x4 b6  = *(const f32x4*)(nbq + (iB1[2] << 7));
            f32x4 b7  = *(const f32x4*)(nbq + (iB1[3] << 7));
            f32x4 b8  = *(const f32x4*)(nbq + (iB2[0] << 7));
            f32x4 b9  = *(const f32x4*)(nbq + (iB2[1] << 7));
            f32x4 b10 = *(const f32x4*)(nbq + (iB2[2] << 7));
            f32x4 b11 = *(const f32x4*)(nbq + (iB2[3] << 7));
            f32x4 b12 = *(const f32x4*)(nbq + (iB3[0] << 7));
            f32x4 b13 = *(const f32x4*)(nbq + (iB3[1] << 7));
            f32x4 b14 = *(const f32x4*)(nbq + (iB3[2] << 7));
            f32x4 b15 = *(const f32x4*)(nbq + (iB3[3] << 7));

            f32x4 s01 = wB0[0] * b0;  s01 += wB0[1] * b1;
            f32x4 s23 = wB0[2] * b2;  s23 += wB0[3] * b3;
            f32x4 s45 = wB1[0] * b4;  s45 += wB1[1] * b5;
            f32x4 s67 = wB1[2] * b6;  s67 += wB1[3] * b7;
            f32x4 s89 = wB2[0] * b8;  s89 += wB2[1] * b9;
            f32x4 sab = wB2[2] * b10; sab += wB2[3] * b11;
            f32x4 scd = wB3[0] * b12; scd += wB3[1] * b13;
            f32x4 sef = wB3[2] * b14; sef += wB3[3] * b15;
            s01 += s23; s45 += s67; s89 += sab; scd += sef;
            s01 += s45; s89 += scd;
            f32x4 acc = s01 + s89;
            bf16x4 xa;
            #pragma unroll
            for (int c = 0; c < 4; ++c) xa[c] = (__bf16)(acc[c] * rv4[c]);
            *(bf16x4*)(Xb + ((kB * 512 + 256 + q * 8) ^ swzB)) = xa;
        }
        red4[g][q] = pagg;
    }
    __syncthreads();
    if (t < 32) {
        f32x4 s = red4[0][t];
        #pragma unroll
        for (int g = 1; g < 8; ++g) s += red4[g][t];
        const f32x4 rv4 = *(const f32x4*)&relv[t * 4];
        bf16x4 h0a;
        #pragma unroll
        for (int c = 0; c < 4; ++c) h0a[c] = (__bf16)(s[c] * rv4[c]);
        *(bf16x4*)(Xb + 16 * 512 + 256 + t * 8) = h0a;   // row16 agg half
    }
    __syncthreads();

    // ---------- Phase E: MFMA  P = X @ [Ws0;Wn0] ----------
    const int w = t >> 6, l = t & 63;
    f32x4 acc00 = {0.f, 0.f, 0.f, 0.f};
    f32x4 acc01 = {0.f, 0.f, 0.f, 0.f};
    f32x4 acc10 = {0.f, 0.f, 0.f, 0.f};
    f32x4 acc11 = {0.f, 0.f, 0.f, 0.f};
    {
        const int row0 = l & 15;
        const int kb   = (l >> 4) * 16;
        const int sw0  = (row0 & 7) << 4;
        #pragma unroll
        for (int s = 0; s < 8; ++s) {
            bf16x8 a0 = *(const bf16x8*)(Xb + ((row0 * 512 + s * 64 + kb) ^ sw0));
            bf16x8 a1 = *(const bf16x8*)(Xb + (16 * 512 + s * 64 + kb));
            bf16x8 b0 = *(const bf16x8*)(packW0 + (((s * 8 + 2 * w) * 64 + l) * 8));
            bf16x8 b1 = *(const bf16x8*)(packW0 + (((s * 8 + 2 * w + 1) * 64 + l) * 8));
            acc00 = __builtin_amdgcn_mfma_f32_16x16x32_bf16(a0, b0, acc00, 0, 0, 0);
            acc01 = __builtin_amdgcn_mfma_f32_16x16x32_bf16(a0, b1, acc01, 0, 0, 0);
            acc10 = __builtin_amdgcn_mfma_f32_16x16x32_bf16(a1, b0, acc10, 0, 0, 0);
            acc11 = __builtin_amdgcn_mfma_f32_16x16x32_bf16(a1, b1, acc11, 0, 0, 0);
        }
    }

    // ---------- Phase F: in-register relu + weighted agg ----------
    {
        const int rbase = (l >> 4) * 4;
        float s0 = 0.f, s1 = 0.f;
        #pragma unroll
        for (int r = 0; r < 4; ++r) {
            float wk = sw00[rbase + r];
            s0 = fmaf(wk, fmaxf(acc00[r], 0.f), s0);
            s1 = fmaf(wk, fmaxf(acc01[r], 0.f), s1);
        }
        s0 += __shfl_xor(s0, 16); s0 += __shfl_xor(s0, 32);
        s1 += __shfl_xor(s1, 16); s1 += __shfl_xor(s1, 32);
        if (l < 16) {
            int c0 = (2 * w) * 16 + l, c1 = (2 * w + 1) * 16 + l;
            y1[c0] = s0;
            y1[c1] = s1;
            y0[c0] = fmaxf(acc10[0], 0.f);
            y0[c1] = fmaxf(acc11[0], 0.f);
        }
    }
    __syncthreads();

    // ---------- Phase H: float4 fp32 final matmul ----------
    {
        const int q = t & 31;
        const int g = t >> 5;
        const int d0 = g * 16;
        f32x4 a = {0.f, 0.f, 0.f, 0.f};
        #pragma unroll
        for (int dq = 0; dq < 4; ++dq) {
            f32x4 ys = *(const f32x4*)&y0[d0 + dq * 4];
            f32x4 ya = *(const f32x4*)&y1[d0 + dq * 4];
            #pragma unroll
            for (int jj = 0; jj < 4; ++jj) {
                const int d = d0 + dq * 4 + jj;
                f32x4 ws = *(const f32x4*)(Ws1 + d * EMB + q * 4);
                f32x4 wn = *(const f32x4*)(Wn1 + d * EMB + q * 4);
                a += ys[jj] * ws;
                a += ya[jj] * wn;
            }
        }
        red4[g][q] = a;
    }
    __syncthreads();

    // ---------- Phase I: L2 normalize + write ----------
    if (t < 32) {
        f32x4 o = red4[0][t];
        #pragma unroll
        for (int g = 1; g < 8; ++g) o += red4[g][t];
        float sq = o[0] * o[0] + o[1] * o[1] + o[2] * o[2] + o[3] * o[3];
        #pragma unroll
        for (int off = 1; off < 32; off <<= 1) sq += __shfl_xor(sq, off);
        float inv = 1.f / fmaxf(sqrtf(sq), 1e-12f);
        o *= inv;
        *(f32x4*)(out + b * EMB + t * 4) = o;
    }
}

extern "C" void kernel_launch(void* const* d_in, const int* in_sizes, int n_in,
                              void* d_out, int out_size, void* d_ws, size_t ws_size,
                              hipStream_t stream) {
    (void)n_in; (void)out_size; (void)ws_size;
    const int*   node      = (const int*)d_in[0];
    const int*   relation  = (const int*)d_in[1];
    const int*   adj_node  = (const int*)d_in[2];
    const int*   adj_rela  = (const int*)d_in[3];
    const int*   node_type = (const int*)d_in[4];
    const float* node_emb  = (const float*)d_in[5];
    const float* rela_emb  = (const float*)d_in[6];
    const float* type_w    = (const float*)d_in[7];
    const float* Ws0       = (const float*)d_in[8];
    const float* Wn0       = (const float*)d_in[9];
    const float* Ws1       = (const float*)d_in[10];
    const float* Wn1       = (const float*)d_in[11];
    float* out = (float*)d_out;
    const int B = in_sizes[0];

    __bf16* packW0 = (__bf16*)d_ws;   // 4096 frags * 8 bf16 = 64 KB

    pack_w_kernel<<<16, 256, 0, stream>>>(Ws0, Wn0, packW0);
    gnn_kernel<<<B, 256, 0, stream>>>(node, relation, adj_node, adj_rela, node_type,
                                      node_emb, rela_emb, type_w, Ws1, Wn1, packW0, out);
}

// Round 5
// 99.716 us; speedup vs baseline: 1.3840x; 1.3840x over previous
//
#include <hip/hip_runtime.h>
#include <math.h>

#define NB   16
#define EMB  128

typedef __bf16 bf16x8 __attribute__((ext_vector_type(8)));
typedef __bf16 bf16x4 __attribute__((ext_vector_type(4)));
typedef float  f32x4  __attribute__((ext_vector_type(4)));
typedef int    i32x4  __attribute__((ext_vector_type(4)));

// ---------------------------------------------------------------------------
// Prep 1: pack [Ws0; Wn0] (K=256 x N=128) as bf16 MFMA B-fragments.
// frag (s,nt) at pack[((s*8+nt)*64 + lane)*8 + j] holds
// W[k = s*32 + (lane>>4)*8 + j][col = nt*16 + (lane&15)].
// ---------------------------------------------------------------------------
__global__ __launch_bounds__(256) void pack_w_kernel(
    const float* __restrict__ Ws0, const float* __restrict__ Wn0,
    __bf16* __restrict__ pack)
{
    int idx = blockIdx.x * 256 + threadIdx.x;   // (s<<9)|(nt<<6)|lane
    if (idx >= 4096) return;
    int l  = idx & 63;
    int nt = (idx >> 6) & 7;
    int s  = idx >> 9;
    int col = nt * 16 + (l & 15);
    int k0  = s * 32 + (l >> 4) * 8;
    bf16x8 v;
    #pragma unroll
    for (int j = 0; j < 8; ++j) {
        int k = k0 + j;
        float wv = (k < 128) ? Ws0[k * EMB + col] : Wn0[(k - 128) * EMB + col];
        v[j] = (__bf16)wv;
    }
    *(bf16x8*)(pack + idx * 8) = v;
}

// ---------------------------------------------------------------------------
// Prep 2: node_emb (fp32) -> bf16 table. Streaming, memory-bound.
// Halves the random-gather L2-miss bytes in the main kernel.
// ---------------------------------------------------------------------------
__global__ __launch_bounds__(256) void conv_emb_kernel(
    const float* __restrict__ src, __bf16* __restrict__ dst, int n4)
{
    int i = blockIdx.x * 256 + threadIdx.x;
    if (i >= n4) return;
    f32x4 v = ((const f32x4*)src)[i];
    bf16x4 o;
    o[0] = (__bf16)v[0]; o[1] = (__bf16)v[1];
    o[2] = (__bf16)v[2]; o[3] = (__bf16)v[3];
    ((bf16x4*)dst)[i] = o;
}

// Row-quad loader: one 8B (bf16) or 16B (fp32) load of cols [4q..4q+3] of row idx.
template<bool BT>
__device__ __forceinline__ f32x4 load_rq(const void* tab, int idx, int q) {
    if constexpr (BT) {
        bf16x4 v = *((const bf16x4*)tab + idx * 32 + q);
        f32x4 r;
        r[0] = (float)v[0]; r[1] = (float)v[1];
        r[2] = (float)v[2]; r[3] = (float)v[3];
        return r;
    } else {
        return *((const f32x4*)tab + idx * 32 + q);
    }
}

// ---------------------------------------------------------------------------
// Main fused kernel: one block (256 thr = 4 waves) per batch element.
// R3 structure (best so far); gathers go through the bf16 table when it fits
// in d_ws (BT=true), else fp32 fallback identical to R3.
// ---------------------------------------------------------------------------
template<bool BT>
__global__ __launch_bounds__(256, 4) void gnn_kernel(
    const int* __restrict__ node, const int* __restrict__ relation,
    const int* __restrict__ adj_node, const int* __restrict__ adj_rela,
    const int* __restrict__ node_type, const void* __restrict__ tab,
    const float* __restrict__ rela_emb, const float* __restrict__ type_w,
    const float* __restrict__ Ws1, const float* __restrict__ Wn1,
    const __bf16* __restrict__ packW0,
    float* __restrict__ out)
{
    // X: row r in [0,17), col c in [0,256): byte = (r*512 + c*2) ^ ((r&7)<<4)
    __shared__ __align__(16) unsigned char Xb[17 * 512];
    __shared__ __align__(16) float sw01[16][16];
    __shared__ __align__(16) int   se2[16][16];
    __shared__ __align__(16) float relv[EMB];
    __shared__ __align__(16) f32x4 red4[8][32];   // D: agg0 partials; H: out partials
    __shared__ __align__(16) float y0[EMB];       // v0
    __shared__ __align__(16) float y1[EMB];       // aggf
    __shared__ float sw00[16];
    __shared__ float srsim[16];
    __shared__ float sdij[16], sdrr[16];
    __shared__ int   se1[16], sr1[16], st1[16];

    const int t   = threadIdx.x;
    const int b   = blockIdx.x;
    const int nb0 = node[b];
    const int rel = relation[b];

    // ---------- Phase A ----------
    if (t < 16) {
        int e1 = adj_node[nb0 * NB + t];
        se1[t] = e1;
        sr1[t] = adj_rela[nb0 * NB + t];
        st1[t] = node_type[e1];
    }
    if (t < EMB) relv[t] = rela_emb[rel * EMB + t];
    {
        int r = t >> 4, c = t & 15;
        float dij = 0.f, drr = 0.f;
        #pragma unroll
        for (int dd = 0; dd < 8; ++dd) {
            int d = dd * 16 + c;
            float a  = rela_emb[rel * EMB + d];
            float bb = rela_emb[r * EMB + d];
            dij = fmaf(a, bb, dij);
            drr = fmaf(bb, bb, drr);
        }
        #pragma unroll
        for (int off = 8; off >= 1; off >>= 1) {
            dij += __shfl_xor(dij, off);
            drr += __shfl_xor(drr, off);
        }
        if (c == 0) { sdij[r] = dij; sdrr[r] = drr; }
    }
    __syncthreads();

    // ---------- Phase B ----------
    if (t < 16) {
        float nrel = fmaxf(sqrtf(sdrr[rel]), 1e-8f);
        float nr   = fmaxf(sqrtf(sdrr[t]),   1e-8f);
        srsim[t] = fabsf(sdij[t]) / (nr * nrel);
    }
    __syncthreads();

    // ---------- Phase C: scores + softmax ----------
    {
        int k = t >> 4, j = t & 15;
        int e1k = se1[k];
        int e2  = adj_node[e1k * NB + j];
        int r2  = adj_rela[e1k * NB + j];
        int t2  = node_type[e2];
        se2[k][j] = e2;
        float s = srsim[r2] * type_w[st1[k] * 4 + t2];
        float m = s;
        #pragma unroll
        for (int off = 8; off >= 1; off >>= 1) m = fmaxf(m, __shfl_xor(m, off));
        float ex = __expf(s - m);
        float sum = ex;
        #pragma unroll
        for (int off = 8; off >= 1; off >>= 1) sum += __shfl_xor(sum, off);
        sw01[k][j] = ex / sum;
    }
    {
        int t0type = node_type[nb0];
        if (t < 16) {
            float s = srsim[sr1[t]] * type_w[t0type * 4 + st1[t]];
            float m = s;
            #pragma unroll
            for (int off = 8; off >= 1; off >>= 1) m = fmaxf(m, __shfl_xor(m, off));
            float ex = __expf(s - m);
            float sum = ex;
            #pragma unroll
            for (int off = 8; off >= 1; off >>= 1) sum += __shfl_xor(sum, off);
            sw00[t] = ex / sum;
        }
    }
    __syncthreads();

    // ---------- Phase D: row-quad gather -> X rows ----------
    {
        const int q = t & 31;     // col quad: cols 4q..4q+3
        const int g = t >> 5;     // 0..7 -> k in {g, g+8}
        const f32x4 rv4 = *(const f32x4*)&relv[q * 4];
        f32x4 pagg = {0.f, 0.f, 0.f, 0.f};

        for (int kx = 0; kx < 2; ++kx) {
            const int k = g + kx * 8;
            const int swz = (k & 7) << 4;

            // self row
            const f32x4 sv = load_rq<BT>(tab, se1[k], q);
            const float wk0 = sw00[k];
            pagg += wk0 * sv;
            bf16x4 xs;
            xs[0] = (__bf16)(sv[0] * rv4[0]);
            xs[1] = (__bf16)(sv[1] * rv4[1]);
            xs[2] = (__bf16)(sv[2] * rv4[2]);
            xs[3] = (__bf16)(sv[3] * rv4[3]);
            *(bf16x4*)(Xb + ((k * 512 + q * 8) ^ swz)) = xs;

            // neighbor indices + weights (broadcast ds_read_b128)
            i32x4 i0 = *(const i32x4*)&se2[k][0];
            i32x4 i1 = *(const i32x4*)&se2[k][4];
            i32x4 i2 = *(const i32x4*)&se2[k][8];
            i32x4 i3 = *(const i32x4*)&se2[k][12];
            f32x4 w0 = *(const f32x4*)&sw01[k][0];
            f32x4 w1 = *(const f32x4*)&sw01[k][4];
            f32x4 w2 = *(const f32x4*)&sw01[k][8];
            f32x4 w3 = *(const f32x4*)&sw01[k][12];

            // issue all 16 row loads, then combine
            f32x4 v0  = load_rq<BT>(tab, i0[0], q);
            f32x4 v1  = load_rq<BT>(tab, i0[1], q);
            f32x4 v2  = load_rq<BT>(tab, i0[2], q);
            f32x4 v3  = load_rq<BT>(tab, i0[3], q);
            f32x4 v4  = load_rq<BT>(tab, i1[0], q);
            f32x4 v5  = load_rq<BT>(tab, i1[1], q);
            f32x4 v6  = load_rq<BT>(tab, i1[2], q);
            f32x4 v7  = load_rq<BT>(tab, i1[3], q);
            f32x4 v8  = load_rq<BT>(tab, i2[0], q);
            f32x4 v9  = load_rq<BT>(tab, i2[1], q);
            f32x4 v10 = load_rq<BT>(tab, i2[2], q);
            f32x4 v11 = load_rq<BT>(tab, i2[3], q);
            f32x4 v12 = load_rq<BT>(tab, i3[0], q);
            f32x4 v13 = load_rq<BT>(tab, i3[1], q);
            f32x4 v14 = load_rq<BT>(tab, i3[2], q);
            f32x4 v15 = load_rq<BT>(tab, i3[3], q);

            f32x4 s01 = w0[0] * v0;  s01 += w0[1] * v1;
            f32x4 s23 = w0[2] * v2;  s23 += w0[3] * v3;
            f32x4 s45 = w1[0] * v4;  s45 += w1[1] * v5;
            f32x4 s67 = w1[2] * v6;  s67 += w1[3] * v7;
            f32x4 s89 = w2[0] * v8;  s89 += w2[1] * v9;
            f32x4 sab = w2[2] * v10; sab += w2[3] * v11;
            f32x4 scd = w3[0] * v12; scd += w3[1] * v13;
            f32x4 sef = w3[2] * v14; sef += w3[3] * v15;
            s01 += s23; s45 += s67; s89 += sab; scd += sef;
            s01 += s45; s89 += scd;
            f32x4 acc = s01 + s89;

            bf16x4 xa;
            xa[0] = (__bf16)(acc[0] * rv4[0]);
            xa[1] = (__bf16)(acc[1] * rv4[1]);
            xa[2] = (__bf16)(acc[2] * rv4[2]);
            xa[3] = (__bf16)(acc[3] * rv4[3]);
            *(bf16x4*)(Xb + ((k * 512 + 256 + q * 8) ^ swz)) = xa;
        }
        red4[g][q] = pagg;
    }
    __syncthreads();
    if (t < 32) {
        f32x4 s = red4[0][t];
        #pragma unroll
        for (int g = 1; g < 8; ++g) s += red4[g][t];
        const f32x4 rv4 = *(const f32x4*)&relv[t * 4];
        const f32x4 ev0 = load_rq<BT>(tab, nb0, t);
        bf16x4 h0s, h0a;
        #pragma unroll
        for (int c = 0; c < 4; ++c) {
            h0s[c] = (__bf16)(ev0[c] * rv4[c]);
            h0a[c] = (__bf16)(s[c]   * rv4[c]);
        }
        *(bf16x4*)(Xb + 16 * 512 + t * 8)       = h0s;   // row16 (no swizzle)
        *(bf16x4*)(Xb + 16 * 512 + 256 + t * 8) = h0a;
    }
    __syncthreads();

    // ---------- Phase E: MFMA  P = X @ [Ws0;Wn0] ----------
    const int w = t >> 6, l = t & 63;
    f32x4 acc00 = {0.f, 0.f, 0.f, 0.f};
    f32x4 acc01 = {0.f, 0.f, 0.f, 0.f};
    f32x4 acc10 = {0.f, 0.f, 0.f, 0.f};
    f32x4 acc11 = {0.f, 0.f, 0.f, 0.f};
    {
        const int row0 = l & 15;
        const int kb   = (l >> 4) * 16;
        const int sw0  = (row0 & 7) << 4;
        #pragma unroll
        for (int s = 0; s < 8; ++s) {
            bf16x8 a0 = *(const bf16x8*)(Xb + ((row0 * 512 + s * 64 + kb) ^ sw0));
            bf16x8 a1 = *(const bf16x8*)(Xb + (16 * 512 + s * 64 + kb));
            bf16x8 b0 = *(const bf16x8*)(packW0 + (((s * 8 + 2 * w) * 64 + l) * 8));
            bf16x8 b1 = *(const bf16x8*)(packW0 + (((s * 8 + 2 * w + 1) * 64 + l) * 8));
            acc00 = __builtin_amdgcn_mfma_f32_16x16x32_bf16(a0, b0, acc00, 0, 0, 0);
            acc01 = __builtin_amdgcn_mfma_f32_16x16x32_bf16(a0, b1, acc01, 0, 0, 0);
            acc10 = __builtin_amdgcn_mfma_f32_16x16x32_bf16(a1, b0, acc10, 0, 0, 0);
            acc11 = __builtin_amdgcn_mfma_f32_16x16x32_bf16(a1, b1, acc11, 0, 0, 0);
        }
    }

    // ---------- Phase F: in-register relu + weighted agg ----------
    {
        const int rbase = (l >> 4) * 4;
        float s0 = 0.f, s1 = 0.f;
        #pragma unroll
        for (int r = 0; r < 4; ++r) {
            float wk = sw00[rbase + r];
            s0 = fmaf(wk, fmaxf(acc00[r], 0.f), s0);
            s1 = fmaf(wk, fmaxf(acc01[r], 0.f), s1);
        }
        s0 += __shfl_xor(s0, 16); s0 += __shfl_xor(s0, 32);
        s1 += __shfl_xor(s1, 16); s1 += __shfl_xor(s1, 32);
        if (l < 16) {
            int c0 = (2 * w) * 16 + l, c1 = (2 * w + 1) * 16 + l;
            y1[c0] = s0;
            y1[c1] = s1;
            y0[c0] = fmaxf(acc10[0], 0.f);
            y0[c1] = fmaxf(acc11[0], 0.f);
        }
    }
    __syncthreads();

    // ---------- Phase H: float4 fp32 final matmul ----------
    {
        const int q = t & 31;
        const int g = t >> 5;
        const int d0 = g * 16;
        f32x4 a = {0.f, 0.f, 0.f, 0.f};
        #pragma unroll
        for (int dq = 0; dq < 4; ++dq) {
            f32x4 ys = *(const f32x4*)&y0[d0 + dq * 4];
            f32x4 ya = *(const f32x4*)&y1[d0 + dq * 4];
            #pragma unroll
            for (int jj = 0; jj < 4; ++jj) {
                const int d = d0 + dq * 4 + jj;
                f32x4 ws = *(const f32x4*)(Ws1 + d * EMB + q * 4);
                f32x4 wn = *(const f32x4*)(Wn1 + d * EMB + q * 4);
                a += ys[jj] * ws;
                a += ya[jj] * wn;
            }
        }
        red4[g][q] = a;
    }
    __syncthreads();

    // ---------- Phase I: L2 normalize + write ----------
    if (t < 32) {
        f32x4 o = red4[0][t];
        #pragma unroll
        for (int g = 1; g < 8; ++g) o += red4[g][t];
        float sq = o[0] * o[0] + o[1] * o[1] + o[2] * o[2] + o[3] * o[3];
        #pragma unroll
        for (int off = 1; off < 32; off <<= 1) sq += __shfl_xor(sq, off);
        float inv = 1.f / fmaxf(sqrtf(sq), 1e-12f);
        o *= inv;
        *(f32x4*)(out + b * EMB + t * 4) = o;
    }
}

extern "C" void kernel_launch(void* const* d_in, const int* in_sizes, int n_in,
                              void* d_out, int out_size, void* d_ws, size_t ws_size,
                              hipStream_t stream) {
    (void)n_in; (void)out_size;
    const int*   node      = (const int*)d_in[0];
    const int*   relation  = (const int*)d_in[1];
    const int*   adj_node  = (const int*)d_in[2];
    const int*   adj_rela  = (const int*)d_in[3];
    const int*   node_type = (const int*)d_in[4];
    const float* node_emb  = (const float*)d_in[5];
    const float* rela_emb  = (const float*)d_in[6];
    const float* type_w    = (const float*)d_in[7];
    const float* Ws0       = (const float*)d_in[8];
    const float* Wn0       = (const float*)d_in[9];
    const float* Ws1       = (const float*)d_in[10];
    const float* Wn1       = (const float*)d_in[11];
    float* out = (float*)d_out;
    const int B     = in_sizes[0];
    const int nnode = in_sizes[5] / EMB;

    __bf16* packW0 = (__bf16*)d_ws;                       // 64 KB
    __bf16* tabbf  = (__bf16*)((char*)d_ws + 65536);      // nnode*256 B
    const size_t need = 65536 + (size_t)nnode * EMB * 2;

    pack_w_kernel<<<16, 256, 0, stream>>>(Ws0, Wn0, packW0);

    if (ws_size >= need) {
        const int n4 = nnode * EMB / 4;
        conv_emb_kernel<<<(n4 + 255) / 256, 256, 0, stream>>>(node_emb, tabbf, n4);
        gnn_kernel<true><<<B, 256, 0, stream>>>(node, relation, adj_node, adj_rela,
                                                node_type, (const void*)tabbf, rela_emb,
                                                type_w, Ws1, Wn1, packW0, out);
    } else {
        gnn_kernel<false><<<B, 256, 0, stream>>>(node, relation, adj_node, adj_rela,
                                                 node_type, (const void*)node_emb, rela_emb,
                                                 type_w, Ws1, Wn1, packW0, out);
    }
}

// Round 6
// 99.108 us; speedup vs baseline: 1.3924x; 1.0061x over previous
//
#include <hip/hip_runtime.h>
#include <math.h>

#define NB   16
#define EMB  128
#define G    2                    // batch elements per block
#define XSTRIDE 8704              // 17 rows * 512 B per element

typedef __bf16 bf16x8 __attribute__((ext_vector_type(8)));
typedef __bf16 bf16x4 __attribute__((ext_vector_type(4)));
typedef float  f32x4  __attribute__((ext_vector_type(4)));
typedef int    i32x4  __attribute__((ext_vector_type(4)));

// ---------------------------------------------------------------------------
// Prep 1: pack [Ws0;Wn0] and [Ws1;Wn1] (each K=256 x N=128) as bf16 B-frags.
// frag (m,s,nt) at pack[(m*4096 + s*512 + nt*64 + lane)*8 + j] holds
// W_m[k = s*32 + (lane>>4)*8 + j][col = nt*16 + (lane&15)].
// ---------------------------------------------------------------------------
__global__ __launch_bounds__(256) void pack_w_kernel(
    const float* __restrict__ Ws0, const float* __restrict__ Wn0,
    const float* __restrict__ Ws1, const float* __restrict__ Wn1,
    __bf16* __restrict__ pack)
{
    int idx = blockIdx.x * 256 + threadIdx.x;   // (m<<12)|(s<<9)|(nt<<6)|lane
    if (idx >= 8192) return;
    int l  = idx & 63;
    int nt = (idx >> 6) & 7;
    int s  = (idx >> 9) & 7;
    int m  = idx >> 12;
    int col = nt * 16 + (l & 15);
    int k0  = s * 32 + (l >> 4) * 8;
    const float* Wa = m ? Ws1 : Ws0;
    const float* Wb = m ? Wn1 : Wn0;
    bf16x8 v;
    #pragma unroll
    for (int j = 0; j < 8; ++j) {
        int k = k0 + j;
        float wv = (k < 128) ? Wa[k * EMB + col] : Wb[(k - 128) * EMB + col];
        v[j] = (__bf16)wv;
    }
    *(bf16x8*)(pack + (size_t)idx * 8) = v;
}

// ---------------------------------------------------------------------------
// Prep 2: rsim[16][16] = |cos(rela_emb_r, rela_emb_c)| (one block).
// ---------------------------------------------------------------------------
__global__ __launch_bounds__(256) void rsim_kernel(
    const float* __restrict__ rela_emb, float* __restrict__ rsim)
{
    __shared__ float dd[16][16];
    int t = threadIdx.x, r = t >> 4, c = t & 15;
    float d = 0.f;
    #pragma unroll
    for (int k4 = 0; k4 < 32; ++k4) {
        f32x4 a = *(const f32x4*)(rela_emb + r * EMB + k4 * 4);
        f32x4 b = *(const f32x4*)(rela_emb + c * EMB + k4 * 4);
        d += a[0]*b[0] + a[1]*b[1] + a[2]*b[2] + a[3]*b[3];
    }
    dd[r][c] = d;
    __syncthreads();
    float nr = fmaxf(sqrtf(dd[r][r]), 1e-8f);
    float nc = fmaxf(sqrtf(dd[c][c]), 1e-8f);
    rsim[t] = fabsf(d) / (nr * nc);
}

// ---------------------------------------------------------------------------
// Prep 3: node_emb (fp32) -> bf16 table (halves random-gather miss bytes).
// ---------------------------------------------------------------------------
__global__ __launch_bounds__(256) void conv_emb_kernel(
    const float* __restrict__ src, __bf16* __restrict__ dst, int n4)
{
    int i = blockIdx.x * 256 + threadIdx.x;
    if (i >= n4) return;
    f32x4 v = ((const f32x4*)src)[i];
    bf16x4 o;
    o[0] = (__bf16)v[0]; o[1] = (__bf16)v[1];
    o[2] = (__bf16)v[2]; o[3] = (__bf16)v[3];
    ((bf16x4*)dst)[i] = o;
}

template<bool BT>
__device__ __forceinline__ f32x4 load_rq(const void* tab, int idx, int q) {
    if constexpr (BT) {
        bf16x4 v = *((const bf16x4*)tab + idx * 32 + q);
        f32x4 r;
        r[0] = (float)v[0]; r[1] = (float)v[1];
        r[2] = (float)v[2]; r[3] = (float)v[3];
        return r;
    } else {
        return *((const f32x4*)tab + idx * 32 + q);
    }
}

// ---------------------------------------------------------------------------
// Main fused kernel: one block (256 thr = 4 waves) per G=2 batch elements.
// Per element: A (indices/relv/rsim-row) -> C (score softmax) -> D (gather->X).
// Then combined: E (MFMA, B-frags amortized over G), post-E (relu/agg -> Y),
// H (MFMA with packW1, G rows in one M-tile), normalize.
// ---------------------------------------------------------------------------
template<bool BT>
__global__ __launch_bounds__(256, 4) void gnn_kernel(
    const int* __restrict__ node, const int* __restrict__ relation,
    const int* __restrict__ adj_node, const int* __restrict__ adj_rela,
    const int* __restrict__ node_type, const void* __restrict__ tab,
    const float* __restrict__ rela_emb, const float* __restrict__ type_w,
    const __bf16* __restrict__ packW, const float* __restrict__ rsimg,
    float* __restrict__ out)
{
    // X[e]: row r in [0,17), col c in [0,256): byte = (r*512 + c*2) ^ ((r&7)<<4)
    __shared__ __align__(16) unsigned char Xb[G * XSTRIDE];
    __shared__ __align__(16) unsigned char Yb[16 * 512];  // [row][256] bf16, swizzled
    __shared__ __align__(16) float scratch[1024];         // D: pagg partials; H: out rows
    __shared__ __align__(16) float sw01[16][16];
    __shared__ __align__(16) int   se2[16][16];
    __shared__ __align__(16) float relv[EMB];
    __shared__ float sw00[G][16];
    __shared__ float srsim[16];
    __shared__ int   se1[16], sr1[16], st1[16];

    const int t  = threadIdx.x;
    const int b0 = blockIdx.x * G;

    // zero Y rows (rows >= G must be 0 for the M-tile-stuffed final MFMA)
    {
        f32x4 z = {0.f, 0.f, 0.f, 0.f};
        *(f32x4*)(Yb + t * 16)        = z;
        *(f32x4*)(Yb + 4096 + t * 16) = z;
    }

    for (int e = 0; e < G; ++e) {
        const int nb0 = node[b0 + e];
        const int rel = relation[b0 + e];

        // ---------- Phase A ----------
        if (t < 16) {
            int e1 = adj_node[nb0 * NB + t];
            se1[t] = e1;
            sr1[t] = adj_rela[nb0 * NB + t];
            st1[t] = node_type[e1];
            srsim[t] = rsimg[rel * 16 + t];
        }
        if (t < EMB) relv[t] = rela_emb[rel * EMB + t];
        __syncthreads();

        // ---------- Phase C: scores + softmax ----------
        {
            int k = t >> 4, j = t & 15;
            int e1k = se1[k];
            int e2  = adj_node[e1k * NB + j];
            int r2  = adj_rela[e1k * NB + j];
            int t2  = node_type[e2];
            se2[k][j] = e2;
            float s = srsim[r2] * type_w[st1[k] * 4 + t2];
            float m = s;
            #pragma unroll
            for (int off = 8; off >= 1; off >>= 1) m = fmaxf(m, __shfl_xor(m, off));
            float ex = __expf(s - m);
            float sum = ex;
            #pragma unroll
            for (int off = 8; off >= 1; off >>= 1) sum += __shfl_xor(sum, off);
            sw01[k][j] = ex / sum;
        }
        {
            int t0type = node_type[nb0];
            if (t < 16) {
                float s = srsim[sr1[t]] * type_w[t0type * 4 + st1[t]];
                float m = s;
                #pragma unroll
                for (int off = 8; off >= 1; off >>= 1) m = fmaxf(m, __shfl_xor(m, off));
                float ex = __expf(s - m);
                float sum = ex;
                #pragma unroll
                for (int off = 8; off >= 1; off >>= 1) sum += __shfl_xor(sum, off);
                sw00[e][t] = ex / sum;
            }
        }
        __syncthreads();

        // ---------- Phase D: row-quad gather -> X[e] ----------
        unsigned char* Xe = Xb + e * XSTRIDE;
        {
            const int q = t & 31;
            const int g = t >> 5;
            const f32x4 rv4 = *(const f32x4*)&relv[q * 4];
            f32x4 pagg = {0.f, 0.f, 0.f, 0.f};

            for (int kx = 0; kx < 2; ++kx) {
                const int k = g + kx * 8;
                const int swz = (k & 7) << 4;

                const f32x4 sv = load_rq<BT>(tab, se1[k], q);
                pagg += sw00[e][k] * sv;
                bf16x4 xs;
                xs[0] = (__bf16)(sv[0] * rv4[0]);
                xs[1] = (__bf16)(sv[1] * rv4[1]);
                xs[2] = (__bf16)(sv[2] * rv4[2]);
                xs[3] = (__bf16)(sv[3] * rv4[3]);
                *(bf16x4*)(Xe + ((k * 512 + q * 8) ^ swz)) = xs;

                i32x4 i0 = *(const i32x4*)&se2[k][0];
                i32x4 i1 = *(const i32x4*)&se2[k][4];
                i32x4 i2 = *(const i32x4*)&se2[k][8];
                i32x4 i3 = *(const i32x4*)&se2[k][12];
                f32x4 w0 = *(const f32x4*)&sw01[k][0];
                f32x4 w1 = *(const f32x4*)&sw01[k][4];
                f32x4 w2 = *(const f32x4*)&sw01[k][8];
                f32x4 w3 = *(const f32x4*)&sw01[k][12];

                f32x4 v0  = load_rq<BT>(tab, i0[0], q);
                f32x4 v1  = load_rq<BT>(tab, i0[1], q);
                f32x4 v2  = load_rq<BT>(tab, i0[2], q);
                f32x4 v3  = load_rq<BT>(tab, i0[3], q);
                f32x4 v4  = load_rq<BT>(tab, i1[0], q);
                f32x4 v5  = load_rq<BT>(tab, i1[1], q);
                f32x4 v6  = load_rq<BT>(tab, i1[2], q);
                f32x4 v7  = load_rq<BT>(tab, i1[3], q);
                f32x4 v8  = load_rq<BT>(tab, i2[0], q);
                f32x4 v9  = load_rq<BT>(tab, i2[1], q);
                f32x4 v10 = load_rq<BT>(tab, i2[2], q);
                f32x4 v11 = load_rq<BT>(tab, i2[3], q);
                f32x4 v12 = load_rq<BT>(tab, i3[0], q);
                f32x4 v13 = load_rq<BT>(tab, i3[1], q);
                f32x4 v14 = load_rq<BT>(tab, i3[2], q);
                f32x4 v15 = load_rq<BT>(tab, i3[3], q);

                f32x4 s01 = w0[0] * v0;  s01 += w0[1] * v1;
                f32x4 s23 = w0[2] * v2;  s23 += w0[3] * v3;
                f32x4 s45 = w1[0] * v4;  s45 += w1[1] * v5;
                f32x4 s67 = w1[2] * v6;  s67 += w1[3] * v7;
                f32x4 s89 = w2[0] * v8;  s89 += w2[1] * v9;
                f32x4 sab = w2[2] * v10; sab += w2[3] * v11;
                f32x4 scd = w3[0] * v12; scd += w3[1] * v13;
                f32x4 sef = w3[2] * v14; sef += w3[3] * v15;
                s01 += s23; s45 += s67; s89 += sab; scd += sef;
                s01 += s45; s89 += scd;
                f32x4 acc = s01 + s89;

                bf16x4 xa;
                xa[0] = (__bf16)(acc[0] * rv4[0]);
                xa[1] = (__bf16)(acc[1] * rv4[1]);
                xa[2] = (__bf16)(acc[2] * rv4[2]);
                xa[3] = (__bf16)(acc[3] * rv4[3]);
                *(bf16x4*)(Xe + ((k * 512 + 256 + q * 8) ^ swz)) = xa;
            }
            ((f32x4*)scratch)[g * 32 + q] = pagg;
        }
        __syncthreads();
        if (t < 32) {
            f32x4 s = ((f32x4*)scratch)[t];
            #pragma unroll
            for (int g = 1; g < 8; ++g) s += ((f32x4*)scratch)[g * 32 + t];
            const f32x4 rv4 = *(const f32x4*)&relv[t * 4];
            const f32x4 ev0 = load_rq<BT>(tab, nb0, t);
            bf16x4 h0s, h0a;
            #pragma unroll
            for (int c = 0; c < 4; ++c) {
                h0s[c] = (__bf16)(ev0[c] * rv4[c]);
                h0a[c] = (__bf16)(s[c]   * rv4[c]);
            }
            *(bf16x4*)(Xe + 16 * 512 + t * 8)       = h0s;   // row16 (no swizzle)
            *(bf16x4*)(Xe + 16 * 512 + 256 + t * 8) = h0a;
        }
        __syncthreads();
    }

    // ---------- Phase E: MFMA  P[e] = X[e] @ [Ws0;Wn0], B-frags shared ----------
    const int w = t >> 6, l = t & 63;
    f32x4 acc[G][2][2];
    #pragma unroll
    for (int e = 0; e < G; ++e)
        #pragma unroll
        for (int m = 0; m < 2; ++m)
            #pragma unroll
            for (int n = 0; n < 2; ++n)
                acc[e][m][n] = (f32x4){0.f, 0.f, 0.f, 0.f};
    {
        const int row0 = l & 15;
        const int kb   = (l >> 4) * 16;
        const int sw0  = (row0 & 7) << 4;
        #pragma unroll
        for (int s = 0; s < 8; ++s) {
            bf16x8 bf0 = *(const bf16x8*)(packW + ((s * 8 + 2 * w) * 64 + l) * 8);
            bf16x8 bf1 = *(const bf16x8*)(packW + ((s * 8 + 2 * w + 1) * 64 + l) * 8);
            #pragma unroll
            for (int e = 0; e < G; ++e) {
                const unsigned char* Xe = Xb + e * XSTRIDE;
                bf16x8 a0 = *(const bf16x8*)(Xe + ((row0 * 512 + s * 64 + kb) ^ sw0));
                bf16x8 a1 = *(const bf16x8*)(Xe + (16 * 512 + s * 64 + kb));
                acc[e][0][0] = __builtin_amdgcn_mfma_f32_16x16x32_bf16(a0, bf0, acc[e][0][0], 0, 0, 0);
                acc[e][0][1] = __builtin_amdgcn_mfma_f32_16x16x32_bf16(a0, bf1, acc[e][0][1], 0, 0, 0);
                acc[e][1][0] = __builtin_amdgcn_mfma_f32_16x16x32_bf16(a1, bf0, acc[e][1][0], 0, 0, 0);
                acc[e][1][1] = __builtin_amdgcn_mfma_f32_16x16x32_bf16(a1, bf1, acc[e][1][1], 0, 0, 0);
            }
        }
    }

    // ---------- post-E: relu + w00-agg -> Y rows ([v0 | aggf] per element) ----------
    #pragma unroll
    for (int e = 0; e < G; ++e) {
        const int rbase = (l >> 4) * 4;
        float s0 = 0.f, s1 = 0.f;
        #pragma unroll
        for (int r = 0; r < 4; ++r) {
            float wk = sw00[e][rbase + r];
            s0 = fmaf(wk, fmaxf(acc[e][0][0][r], 0.f), s0);
            s1 = fmaf(wk, fmaxf(acc[e][0][1][r], 0.f), s1);
        }
        s0 += __shfl_xor(s0, 16); s0 += __shfl_xor(s0, 32);
        s1 += __shfl_xor(s1, 16); s1 += __shfl_xor(s1, 32);
        if (l < 16) {
            int c0 = 2 * w * 16 + l, c1 = c0 + 16;
            const int swz = (e & 7) << 4;
            *(__bf16*)(Yb + ((e * 512 + c0 * 2) ^ swz))         = (__bf16)fmaxf(acc[e][1][0][0], 0.f);
            *(__bf16*)(Yb + ((e * 512 + c1 * 2) ^ swz))         = (__bf16)fmaxf(acc[e][1][1][0], 0.f);
            *(__bf16*)(Yb + ((e * 512 + (128 + c0) * 2) ^ swz)) = (__bf16)s0;
            *(__bf16*)(Yb + ((e * 512 + (128 + c1) * 2) ^ swz)) = (__bf16)s1;
        }
    }
    __syncthreads();

    // ---------- Phase H: out rows = Y @ [Ws1;Wn1] (one stuffed M-tile) ----------
    {
        f32x4 h0 = {0.f, 0.f, 0.f, 0.f};
        f32x4 h1 = {0.f, 0.f, 0.f, 0.f};
        const int row0 = l & 15;
        const int kb   = (l >> 4) * 16;
        const int sw0  = (row0 & 7) << 4;
        const __bf16* packW1 = packW + 32768;
        #pragma unroll
        for (int s = 0; s < 8; ++s) {
            bf16x8 a   = *(const bf16x8*)(Yb + ((row0 * 512 + s * 64 + kb) ^ sw0));
            bf16x8 bf0 = *(const bf16x8*)(packW1 + ((s * 8 + 2 * w) * 64 + l) * 8);
            bf16x8 bf1 = *(const bf16x8*)(packW1 + ((s * 8 + 2 * w + 1) * 64 + l) * 8);
            h0 = __builtin_amdgcn_mfma_f32_16x16x32_bf16(a, bf0, h0, 0, 0, 0);
            h1 = __builtin_amdgcn_mfma_f32_16x16x32_bf16(a, bf1, h1, 0, 0, 0);
        }
        if (l < 16) {   // D rows = (l>>4)*4 + reg -> rows 0..3; row e = element e
            int c0 = 2 * w * 16 + l, c1 = c0 + 16;
            #pragma unroll
            for (int e = 0; e < G; ++e) {
                scratch[e * EMB + c0] = h0[e];
                scratch[e * EMB + c1] = h1[e];
            }
        }
    }
    __syncthreads();

    // ---------- normalize + write ----------
    if (t < 64 * G) {
        int e  = t >> 6;
        int c2 = (t & 63) * 2;
        float a  = scratch[e * EMB + c2];
        float bb = scratch[e * EMB + c2 + 1];
        float sq = a * a + bb * bb;
        #pragma unroll
        for (int off = 1; off < 64; off <<= 1) sq += __shfl_xor(sq, off);
        float inv = 1.f / fmaxf(sqrtf(sq), 1e-12f);
        out[(b0 + e) * EMB + c2]     = a * inv;
        out[(b0 + e) * EMB + c2 + 1] = bb * inv;
    }
}

extern "C" void kernel_launch(void* const* d_in, const int* in_sizes, int n_in,
                              void* d_out, int out_size, void* d_ws, size_t ws_size,
                              hipStream_t stream) {
    (void)n_in; (void)out_size;
    const int*   node      = (const int*)d_in[0];
    const int*   relation  = (const int*)d_in[1];
    const int*   adj_node  = (const int*)d_in[2];
    const int*   adj_rela  = (const int*)d_in[3];
    const int*   node_type = (const int*)d_in[4];
    const float* node_emb  = (const float*)d_in[5];
    const float* rela_emb  = (const float*)d_in[6];
    const float* type_w    = (const float*)d_in[7];
    const float* Ws0       = (const float*)d_in[8];
    const float* Wn0       = (const float*)d_in[9];
    const float* Ws1       = (const float*)d_in[10];
    const float* Wn1       = (const float*)d_in[11];
    float* out = (float*)d_out;
    const int B     = in_sizes[0];
    const int nnode = in_sizes[5] / EMB;

    __bf16* packW = (__bf16*)d_ws;                          // 128 KB (W0 + W1 frags)
    float*  rsimg = (float*)((char*)d_ws + 131072);         // 1 KB
    __bf16* tabbf = (__bf16*)((char*)d_ws + 132096);        // nnode*256 B
    const size_t need = 132096 + (size_t)nnode * EMB * 2;

    pack_w_kernel<<<32, 256, 0, stream>>>(Ws0, Wn0, Ws1, Wn1, packW);
    rsim_kernel<<<1, 256, 0, stream>>>(rela_emb, rsimg);

    const int grid = B / G;
    if (ws_size >= need) {
        const int n4 = nnode * EMB / 4;
        conv_emb_kernel<<<(n4 + 255) / 256, 256, 0, stream>>>(node_emb, tabbf, n4);
        gnn_kernel<true><<<grid, 256, 0, stream>>>(node, relation, adj_node, adj_rela,
                                                   node_type, (const void*)tabbf, rela_emb,
                                                   type_w, packW, rsimg, out);
    } else {
        gnn_kernel<false><<<grid, 256, 0, stream>>>(node, relation, adj_node, adj_rela,
                                                    node_type, (const void*)node_emb, rela_emb,
                                                    type_w, packW, rsimg, out);
    }
}

// Round 7
// 97.699 us; speedup vs baseline: 1.4125x; 1.0144x over previous
//
#include <hip/hip_runtime.h>
#include <math.h>

#define NB   16
#define EMB  128

typedef __bf16 bf16x8 __attribute__((ext_vector_type(8)));
typedef __bf16 bf16x4 __attribute__((ext_vector_type(4)));
typedef float  f32x4  __attribute__((ext_vector_type(4)));
typedef int    i32x4  __attribute__((ext_vector_type(4)));

// ---------------------------------------------------------------------------
// Prep 1: pack [Ws0;Wn0] and [Ws1;Wn1] (each K=256 x N=128) as bf16 B-frags.
// frag (m,s,nt) at pack[(m*4096 + s*512 + nt*64 + lane)*8 + j] holds
// W_m[k = s*32 + (lane>>4)*8 + j][col = nt*16 + (lane&15)].
// ---------------------------------------------------------------------------
__global__ __launch_bounds__(256) void pack_w_kernel(
    const float* __restrict__ Ws0, const float* __restrict__ Wn0,
    const float* __restrict__ Ws1, const float* __restrict__ Wn1,
    __bf16* __restrict__ pack)
{
    int idx = blockIdx.x * 256 + threadIdx.x;   // (m<<12)|(s<<9)|(nt<<6)|lane
    if (idx >= 8192) return;
    int l  = idx & 63;
    int nt = (idx >> 6) & 7;
    int s  = (idx >> 9) & 7;
    int m  = idx >> 12;
    int col = nt * 16 + (l & 15);
    int k0  = s * 32 + (l >> 4) * 8;
    const float* Wa = m ? Ws1 : Ws0;
    const float* Wb = m ? Wn1 : Wn0;
    bf16x8 v;
    #pragma unroll
    for (int j = 0; j < 8; ++j) {
        int k = k0 + j;
        float wv = (k < 128) ? Wa[k * EMB + col] : Wb[(k - 128) * EMB + col];
        v[j] = (__bf16)wv;
    }
    *(bf16x8*)(pack + (size_t)idx * 8) = v;
}

// ---------------------------------------------------------------------------
// Prep 2: rsim[16][16] = |cos(rela_emb_r, rela_emb_c)| (one block).
// ---------------------------------------------------------------------------
__global__ __launch_bounds__(256) void rsim_kernel(
    const float* __restrict__ rela_emb, float* __restrict__ rsim)
{
    __shared__ float dd[16][16];
    int t = threadIdx.x, r = t >> 4, c = t & 15;
    float d = 0.f;
    #pragma unroll
    for (int k4 = 0; k4 < 32; ++k4) {
        f32x4 a = *(const f32x4*)(rela_emb + r * EMB + k4 * 4);
        f32x4 b = *(const f32x4*)(rela_emb + c * EMB + k4 * 4);
        d += a[0]*b[0] + a[1]*b[1] + a[2]*b[2] + a[3]*b[3];
    }
    dd[r][c] = d;
    __syncthreads();
    float nr = fmaxf(sqrtf(dd[r][r]), 1e-8f);
    float nc = fmaxf(sqrtf(dd[c][c]), 1e-8f);
    rsim[t] = fabsf(d) / (nr * nc);
}

// ---------------------------------------------------------------------------
// Prep 3: node_emb (fp32) -> bf16 table (halves random-gather miss bytes).
// ---------------------------------------------------------------------------
__global__ __launch_bounds__(256) void conv_emb_kernel(
    const float* __restrict__ src, __bf16* __restrict__ dst, int n4)
{
    int i = blockIdx.x * 256 + threadIdx.x;
    if (i >= n4) return;
    f32x4 v = ((const f32x4*)src)[i];
    bf16x4 o;
    o[0] = (__bf16)v[0]; o[1] = (__bf16)v[1];
    o[2] = (__bf16)v[2]; o[3] = (__bf16)v[3];
    ((bf16x4*)dst)[i] = o;
}

template<bool BT>
__device__ __forceinline__ f32x4 load_rq(const void* tab, int idx, int q) {
    if constexpr (BT) {
        bf16x4 v = *((const bf16x4*)tab + idx * 32 + q);
        f32x4 r;
        r[0] = (float)v[0]; r[1] = (float)v[1];
        r[2] = (float)v[2]; r[3] = (float)v[3];
        return r;
    } else {
        return *((const f32x4*)tab + idx * 32 + q);
    }
}

// ---------------------------------------------------------------------------
// Main fused kernel: one block (256 thr = 4 waves) per batch element (G=1),
// ~16 KB LDS via aliasing (Y-tile and H-output overlay dead X/scratch) so
// 8 blocks/CU can be resident -> more concurrent gather streams.
// ---------------------------------------------------------------------------
template<bool BT>
__global__ __launch_bounds__(256, 4) void gnn_kernel(
    const int* __restrict__ node, const int* __restrict__ relation,
    const int* __restrict__ adj_node, const int* __restrict__ adj_rela,
    const int* __restrict__ node_type, const void* __restrict__ tab,
    const float* __restrict__ rela_emb, const float* __restrict__ type_w,
    const __bf16* __restrict__ packW, const float* __restrict__ rsimg,
    float* __restrict__ out)
{
    // X: row r in [0,17), col c in [0,256): byte = (r*512 + c*2) ^ ((r&7)<<4)
    // After phase E, rows 0..15 of Xb are reused as the Y-tile (same swizzle).
    __shared__ __align__(16) unsigned char Xb[17 * 512];
    __shared__ __align__(16) f32x4 scr4[8][32];   // D: pagg partials; H: out row (aliased)
    __shared__ __align__(16) float sw01[16][16];
    __shared__ __align__(16) int   se2[16][16];
    __shared__ __align__(16) float relv[EMB];
    __shared__ float sw00[16];
    __shared__ float srsim[16];
    __shared__ int   se1[16], sr1[16], st1[16];

    const int t   = threadIdx.x;
    const int b   = blockIdx.x;
    const int nb0 = node[b];
    const int rel = relation[b];

    // ---------- Phase A ----------
    if (t < 16) {
        int e1 = adj_node[nb0 * NB + t];
        se1[t] = e1;
        sr1[t] = adj_rela[nb0 * NB + t];
        st1[t] = node_type[e1];
        srsim[t] = rsimg[rel * 16 + t];
    }
    if (t < EMB) relv[t] = rela_emb[rel * EMB + t];
    __syncthreads();

    // ---------- Phase C: scores + softmax ----------
    {
        int k = t >> 4, j = t & 15;
        int e1k = se1[k];
        int e2  = adj_node[e1k * NB + j];
        int r2  = adj_rela[e1k * NB + j];
        int t2  = node_type[e2];
        se2[k][j] = e2;
        float s = srsim[r2] * type_w[st1[k] * 4 + t2];
        float m = s;
        #pragma unroll
        for (int off = 8; off >= 1; off >>= 1) m = fmaxf(m, __shfl_xor(m, off));
        float ex = __expf(s - m);
        float sum = ex;
        #pragma unroll
        for (int off = 8; off >= 1; off >>= 1) sum += __shfl_xor(sum, off);
        sw01[k][j] = ex / sum;
    }
    {
        int t0type = node_type[nb0];
        if (t < 16) {
            float s = srsim[sr1[t]] * type_w[t0type * 4 + st1[t]];
            float m = s;
            #pragma unroll
            for (int off = 8; off >= 1; off >>= 1) m = fmaxf(m, __shfl_xor(m, off));
            float ex = __expf(s - m);
            float sum = ex;
            #pragma unroll
            for (int off = 8; off >= 1; off >>= 1) sum += __shfl_xor(sum, off);
            sw00[t] = ex / sum;
        }
    }
    __syncthreads();

    // ---------- Phase D: row-quad gather -> X rows (incl. row16 self half) ----------
    {
        const int q = t & 31;     // col quad: cols 4q..4q+3
        const int g = t >> 5;     // 0..7 -> k in {g, g+8}
        const f32x4 rv4 = *(const f32x4*)&relv[q * 4];
        f32x4 pagg = {0.f, 0.f, 0.f, 0.f};

        if (g == 0) {   // hop-0 self row (row16, no swizzle)
            const f32x4 ev0 = load_rq<BT>(tab, nb0, q);
            bf16x4 h0s;
            #pragma unroll
            for (int c = 0; c < 4; ++c) h0s[c] = (__bf16)(ev0[c] * rv4[c]);
            *(bf16x4*)(Xb + 16 * 512 + q * 8) = h0s;
        }

        for (int kx = 0; kx < 2; ++kx) {
            const int k = g + kx * 8;
            const int swz = (k & 7) << 4;

            const f32x4 sv = load_rq<BT>(tab, se1[k], q);
            pagg += sw00[k] * sv;
            bf16x4 xs;
            xs[0] = (__bf16)(sv[0] * rv4[0]);
            xs[1] = (__bf16)(sv[1] * rv4[1]);
            xs[2] = (__bf16)(sv[2] * rv4[2]);
            xs[3] = (__bf16)(sv[3] * rv4[3]);
            *(bf16x4*)(Xb + ((k * 512 + q * 8) ^ swz)) = xs;

            i32x4 i0 = *(const i32x4*)&se2[k][0];
            i32x4 i1 = *(const i32x4*)&se2[k][4];
            i32x4 i2 = *(const i32x4*)&se2[k][8];
            i32x4 i3 = *(const i32x4*)&se2[k][12];
            f32x4 w0 = *(const f32x4*)&sw01[k][0];
            f32x4 w1 = *(const f32x4*)&sw01[k][4];
            f32x4 w2 = *(const f32x4*)&sw01[k][8];
            f32x4 w3 = *(const f32x4*)&sw01[k][12];

            f32x4 v0  = load_rq<BT>(tab, i0[0], q);
            f32x4 v1  = load_rq<BT>(tab, i0[1], q);
            f32x4 v2  = load_rq<BT>(tab, i0[2], q);
            f32x4 v3  = load_rq<BT>(tab, i0[3], q);
            f32x4 v4  = load_rq<BT>(tab, i1[0], q);
            f32x4 v5  = load_rq<BT>(tab, i1[1], q);
            f32x4 v6  = load_rq<BT>(tab, i1[2], q);
            f32x4 v7  = load_rq<BT>(tab, i1[3], q);
            f32x4 v8  = load_rq<BT>(tab, i2[0], q);
            f32x4 v9  = load_rq<BT>(tab, i2[1], q);
            f32x4 v10 = load_rq<BT>(tab, i2[2], q);
            f32x4 v11 = load_rq<BT>(tab, i2[3], q);
            f32x4 v12 = load_rq<BT>(tab, i3[0], q);
            f32x4 v13 = load_rq<BT>(tab, i3[1], q);
            f32x4 v14 = load_rq<BT>(tab, i3[2], q);
            f32x4 v15 = load_rq<BT>(tab, i3[3], q);

            f32x4 s01 = w0[0] * v0;  s01 += w0[1] * v1;
            f32x4 s23 = w0[2] * v2;  s23 += w0[3] * v3;
            f32x4 s45 = w1[0] * v4;  s45 += w1[1] * v5;
            f32x4 s67 = w1[2] * v6;  s67 += w1[3] * v7;
            f32x4 s89 = w2[0] * v8;  s89 += w2[1] * v9;
            f32x4 sab = w2[2] * v10; sab += w2[3] * v11;
            f32x4 scd = w3[0] * v12; scd += w3[1] * v13;
            f32x4 sef = w3[2] * v14; sef += w3[3] * v15;
            s01 += s23; s45 += s67; s89 += sab; scd += sef;
            s01 += s45; s89 += scd;
            f32x4 acc = s01 + s89;

            bf16x4 xa;
            xa[0] = (__bf16)(acc[0] * rv4[0]);
            xa[1] = (__bf16)(acc[1] * rv4[1]);
            xa[2] = (__bf16)(acc[2] * rv4[2]);
            xa[3] = (__bf16)(acc[3] * rv4[3]);
            *(bf16x4*)(Xb + ((k * 512 + 256 + q * 8) ^ swz)) = xa;
        }
        scr4[g][q] = pagg;
    }
    __syncthreads();
    if (t < 32) {   // row16 agg half
        f32x4 s = scr4[0][t];
        #pragma unroll
        for (int g = 1; g < 8; ++g) s += scr4[g][t];
        const f32x4 rv4 = *(const f32x4*)&relv[t * 4];
        bf16x4 h0a;
        #pragma unroll
        for (int c = 0; c < 4; ++c) h0a[c] = (__bf16)(s[c] * rv4[c]);
        *(bf16x4*)(Xb + 16 * 512 + 256 + t * 8) = h0a;
    }
    __syncthreads();

    // ---------- Phase E: MFMA  P = X @ [Ws0;Wn0] ----------
    const int w = t >> 6, l = t & 63;
    f32x4 acc00 = {0.f, 0.f, 0.f, 0.f};
    f32x4 acc01 = {0.f, 0.f, 0.f, 0.f};
    f32x4 acc10 = {0.f, 0.f, 0.f, 0.f};
    f32x4 acc11 = {0.f, 0.f, 0.f, 0.f};
    {
        const int row0 = l & 15;
        const int kb   = (l >> 4) * 16;
        const int sw0  = (row0 & 7) << 4;
        #pragma unroll
        for (int s = 0; s < 8; ++s) {
            bf16x8 a0 = *(const bf16x8*)(Xb + ((row0 * 512 + s * 64 + kb) ^ sw0));
            bf16x8 a1 = *(const bf16x8*)(Xb + (16 * 512 + s * 64 + kb));
            bf16x8 b0 = *(const bf16x8*)(packW + ((s * 8 + 2 * w) * 64 + l) * 8);
            bf16x8 b1 = *(const bf16x8*)(packW + ((s * 8 + 2 * w + 1) * 64 + l) * 8);
            acc00 = __builtin_amdgcn_mfma_f32_16x16x32_bf16(a0, b0, acc00, 0, 0, 0);
            acc01 = __builtin_amdgcn_mfma_f32_16x16x32_bf16(a0, b1, acc01, 0, 0, 0);
            acc10 = __builtin_amdgcn_mfma_f32_16x16x32_bf16(a1, b0, acc10, 0, 0, 0);
            acc11 = __builtin_amdgcn_mfma_f32_16x16x32_bf16(a1, b1, acc11, 0, 0, 0);
        }
    }
    __syncthreads();   // all reads of X done -> safe to overlay Y

    // ---------- zero Y tile (rows 0..15 of Xb) ----------
    {
        f32x4 z = {0.f, 0.f, 0.f, 0.f};
        *(f32x4*)(Xb + t * 32)      = z;
        *(f32x4*)(Xb + t * 32 + 16) = z;
    }
    __syncthreads();

    // ---------- post-E: relu + w00-agg -> Y row 0 ([v0 | aggf]) ----------
    {
        const int rbase = (l >> 4) * 4;
        float s0 = 0.f, s1 = 0.f;
        #pragma unroll
        for (int r = 0; r < 4; ++r) {
            float wk = sw00[rbase + r];
            s0 = fmaf(wk, fmaxf(acc00[r], 0.f), s0);
            s1 = fmaf(wk, fmaxf(acc01[r], 0.f), s1);
        }
        s0 += __shfl_xor(s0, 16); s0 += __shfl_xor(s0, 32);
        s1 += __shfl_xor(s1, 16); s1 += __shfl_xor(s1, 32);
        if (l < 16) {   // Y row 0: swizzle (0&7)<<4 == 0
            int c0 = 2 * w * 16 + l, c1 = c0 + 16;
            *(__bf16*)(Xb + c0 * 2)         = (__bf16)fmaxf(acc10[0], 0.f);
            *(__bf16*)(Xb + c1 * 2)         = (__bf16)fmaxf(acc11[0], 0.f);
            *(__bf16*)(Xb + (128 + c0) * 2) = (__bf16)s0;
            *(__bf16*)(Xb + (128 + c1) * 2) = (__bf16)s1;
        }
    }
    __syncthreads();

    // ---------- Phase H: out row = Y @ [Ws1;Wn1] (stuffed M-tile) ----------
    float* hout = (float*)scr4;
    {
        f32x4 h0 = {0.f, 0.f, 0.f, 0.f};
        f32x4 h1 = {0.f, 0.f, 0.f, 0.f};
        const int row0 = l & 15;
        const int kb   = (l >> 4) * 16;
        const int sw0  = (row0 & 7) << 4;
        const __bf16* packW1 = packW + 32768;
        #pragma unroll
        for (int s = 0; s < 8; ++s) {
            bf16x8 a   = *(const bf16x8*)(Xb + ((row0 * 512 + s * 64 + kb) ^ sw0));
            bf16x8 b0  = *(const bf16x8*)(packW1 + ((s * 8 + 2 * w) * 64 + l) * 8);
            bf16x8 b1  = *(const bf16x8*)(packW1 + ((s * 8 + 2 * w + 1) * 64 + l) * 8);
            h0 = __builtin_amdgcn_mfma_f32_16x16x32_bf16(a, b0, h0, 0, 0, 0);
            h1 = __builtin_amdgcn_mfma_f32_16x16x32_bf16(a, b1, h1, 0, 0, 0);
        }
        if (l < 16) {   // D row 0 = reg 0 of lanes l<16
            int c0 = 2 * w * 16 + l, c1 = c0 + 16;
            hout[c0] = h0[0];
            hout[c1] = h1[0];
        }
    }
    __syncthreads();

    // ---------- normalize + write ----------
    if (t < 64) {
        float a  = hout[t * 2];
        float bb = hout[t * 2 + 1];
        float sq = a * a + bb * bb;
        #pragma unroll
        for (int off = 1; off < 64; off <<= 1) sq += __shfl_xor(sq, off);
        float inv = 1.f / fmaxf(sqrtf(sq), 1e-12f);
        out[b * EMB + t * 2]     = a * inv;
        out[b * EMB + t * 2 + 1] = bb * inv;
    }
}

extern "C" void kernel_launch(void* const* d_in, const int* in_sizes, int n_in,
                              void* d_out, int out_size, void* d_ws, size_t ws_size,
                              hipStream_t stream) {
    (void)n_in; (void)out_size;
    const int*   node      = (const int*)d_in[0];
    const int*   relation  = (const int*)d_in[1];
    const int*   adj_node  = (const int*)d_in[2];
    const int*   adj_rela  = (const int*)d_in[3];
    const int*   node_type = (const int*)d_in[4];
    const float* node_emb  = (const float*)d_in[5];
    const float* rela_emb  = (const float*)d_in[6];
    const float* type_w    = (const float*)d_in[7];
    const float* Ws0       = (const float*)d_in[8];
    const float* Wn0       = (const float*)d_in[9];
    const float* Ws1       = (const float*)d_in[10];
    const float* Wn1       = (const float*)d_in[11];
    float* out = (float*)d_out;
    const int B     = in_sizes[0];
    const int nnode = in_sizes[5] / EMB;

    __bf16* packW = (__bf16*)d_ws;                          // 128 KB (W0 + W1 frags)
    float*  rsimg = (float*)((char*)d_ws + 131072);         // 1 KB
    __bf16* tabbf = (__bf16*)((char*)d_ws + 132096);        // nnode*256 B
    const size_t need = 132096 + (size_t)nnode * EMB * 2;

    pack_w_kernel<<<32, 256, 0, stream>>>(Ws0, Wn0, Ws1, Wn1, packW);
    rsim_kernel<<<1, 256, 0, stream>>>(rela_emb, rsimg);

    if (ws_size >= need) {
        const int n4 = nnode * EMB / 4;
        conv_emb_kernel<<<(n4 + 255) / 256, 256, 0, stream>>>(node_emb, tabbf, n4);
        gnn_kernel<true><<<B, 256, 0, stream>>>(node, relation, adj_node, adj_rela,
                                                node_type, (const void*)tabbf, rela_emb,
                                                type_w, packW, rsimg, out);
    } else {
        gnn_kernel<false><<<B, 256, 0, stream>>>(node, relation, adj_node, adj_rela,
                                                 node_type, (const void*)node_emb, rela_emb,
                                                 type_w, packW, rsimg, out);
    }
}

// Round 8
// 86.680 us; speedup vs baseline: 1.5921x; 1.1271x over previous
//
#include <hip/hip_runtime.h>
#include <math.h>

#define NB   16
#define EMB  128

typedef __bf16 bf16x8 __attribute__((ext_vector_type(8)));
typedef __bf16 bf16x4 __attribute__((ext_vector_type(4)));
typedef float  f32x4  __attribute__((ext_vector_type(4)));
typedef int    i32x4  __attribute__((ext_vector_type(4)));

// ---------------------------------------------------------------------------
// Unified prep kernel:
//   blocks 0..31 : pack [Ws0;Wn0] and [Ws1;Wn1] as bf16 MFMA B-fragments
//                  frag (m,s,nt) at pack[(m*4096+s*512+nt*64+lane)*8 + j] =
//                  W_m[k=s*32+(lane>>4)*8+j][col=nt*16+(lane&15)]
//   block  32    : rsim[16][16] = |cos(rela_emb_r, rela_emb_c)|
//   blocks 33+   : node_emb fp32 -> bf16 table (streaming)
// ---------------------------------------------------------------------------
__global__ __launch_bounds__(256) void prep_all_kernel(
    const float* __restrict__ Ws0, const float* __restrict__ Wn0,
    const float* __restrict__ Ws1, const float* __restrict__ Wn1,
    const float* __restrict__ rela_emb, const float* __restrict__ node_emb,
    __bf16* __restrict__ pack, float* __restrict__ rsim,
    __bf16* __restrict__ tabbf, int n4)
{
    __shared__ float dd[16][16];
    const int bid = blockIdx.x;
    const int t   = threadIdx.x;

    if (bid < 32) {
        int idx = bid * 256 + t;   // (m<<12)|(s<<9)|(nt<<6)|lane
        int l  = idx & 63;
        int nt = (idx >> 6) & 7;
        int s  = (idx >> 9) & 7;
        int m  = idx >> 12;
        int col = nt * 16 + (l & 15);
        int k0  = s * 32 + (l >> 4) * 8;
        const float* Wa = m ? Ws1 : Ws0;
        const float* Wb = m ? Wn1 : Wn0;
        bf16x8 v;
        #pragma unroll
        for (int j = 0; j < 8; ++j) {
            int k = k0 + j;
            float wv = (k < 128) ? Wa[k * EMB + col] : Wb[(k - 128) * EMB + col];
            v[j] = (__bf16)wv;
        }
        *(bf16x8*)(pack + (size_t)idx * 8) = v;
    } else if (bid == 32) {
        int r = t >> 4, c = t & 15;
        float d = 0.f;
        #pragma unroll
        for (int k4 = 0; k4 < 32; ++k4) {
            f32x4 a = *(const f32x4*)(rela_emb + r * EMB + k4 * 4);
            f32x4 b = *(const f32x4*)(rela_emb + c * EMB + k4 * 4);
            d += a[0]*b[0] + a[1]*b[1] + a[2]*b[2] + a[3]*b[3];
        }
        dd[r][c] = d;
        __syncthreads();
        float nr = fmaxf(sqrtf(dd[r][r]), 1e-8f);
        float nc = fmaxf(sqrtf(dd[c][c]), 1e-8f);
        rsim[t] = fabsf(d) / (nr * nc);
    } else {
        int i = (bid - 33) * 256 + t;
        if (i < n4) {
            f32x4 v = ((const f32x4*)node_emb)[i];
            bf16x4 o;
            o[0] = (__bf16)v[0]; o[1] = (__bf16)v[1];
            o[2] = (__bf16)v[2]; o[3] = (__bf16)v[3];
            ((bf16x4*)tabbf)[i] = o;
        }
    }
}

template<bool BT>
__device__ __forceinline__ f32x4 load_rq(const void* tab, int idx, int q) {
    if constexpr (BT) {
        bf16x4 v = *((const bf16x4*)tab + idx * 32 + q);
        f32x4 r;
        r[0] = (float)v[0]; r[1] = (float)v[1];
        r[2] = (float)v[2]; r[3] = (float)v[3];
        return r;
    } else {
        return *((const f32x4*)tab + idx * 32 + q);
    }
}

// ---------------------------------------------------------------------------
// Main fused kernel: one block (256 thr = 4 waves) per batch element,
// ~16 KB LDS via aliasing. R7 structure; ev0 gather issued at kernel entry.
// ---------------------------------------------------------------------------
template<bool BT>
__global__ __launch_bounds__(256, 4) void gnn_kernel(
    const int* __restrict__ node, const int* __restrict__ relation,
    const int* __restrict__ adj_node, const int* __restrict__ adj_rela,
    const int* __restrict__ node_type, const void* __restrict__ tab,
    const float* __restrict__ rela_emb, const float* __restrict__ type_w,
    const __bf16* __restrict__ packW, const float* __restrict__ rsimg,
    float* __restrict__ out)
{
    // X: row r in [0,17), col c in [0,256): byte = (r*512 + c*2) ^ ((r&7)<<4)
    // After phase E, rows 0..15 of Xb are reused as the Y-tile (same swizzle).
    __shared__ __align__(16) unsigned char Xb[17 * 512];
    __shared__ __align__(16) f32x4 scr4[8][32];   // D: pagg partials; H: out row (aliased)
    __shared__ __align__(16) float sw01[16][16];
    __shared__ __align__(16) int   se2[16][16];
    __shared__ __align__(16) float relv[EMB];
    __shared__ float sw00[16];
    __shared__ float srsim[16];
    __shared__ int   se1[16], sr1[16], st1[16];

    const int t   = threadIdx.x;
    const int b   = blockIdx.x;
    const int nb0 = node[b];
    const int rel = relation[b];

    // hop-0 self row: issue the gather immediately (only depends on nb0)
    const int q0 = t & 31;
    const int g0 = t >> 5;
    f32x4 ev0q = {0.f, 0.f, 0.f, 0.f};
    if (g0 == 0) ev0q = load_rq<BT>(tab, nb0, q0);

    // ---------- Phase A ----------
    if (t < 16) {
        int e1 = adj_node[nb0 * NB + t];
        se1[t] = e1;
        sr1[t] = adj_rela[nb0 * NB + t];
        st1[t] = node_type[e1];
        srsim[t] = rsimg[rel * 16 + t];
    }
    if (t < EMB) relv[t] = rela_emb[rel * EMB + t];
    __syncthreads();

    // ---------- Phase C: scores + softmax ----------
    {
        int k = t >> 4, j = t & 15;
        int e1k = se1[k];
        int e2  = adj_node[e1k * NB + j];
        int r2  = adj_rela[e1k * NB + j];
        int t2  = node_type[e2];
        se2[k][j] = e2;
        float s = srsim[r2] * type_w[st1[k] * 4 + t2];
        float m = s;
        #pragma unroll
        for (int off = 8; off >= 1; off >>= 1) m = fmaxf(m, __shfl_xor(m, off));
        float ex = __expf(s - m);
        float sum = ex;
        #pragma unroll
        for (int off = 8; off >= 1; off >>= 1) sum += __shfl_xor(sum, off);
        sw01[k][j] = ex / sum;
    }
    {
        int t0type = node_type[nb0];
        if (t < 16) {
            float s = srsim[sr1[t]] * type_w[t0type * 4 + st1[t]];
            float m = s;
            #pragma unroll
            for (int off = 8; off >= 1; off >>= 1) m = fmaxf(m, __shfl_xor(m, off));
            float ex = __expf(s - m);
            float sum = ex;
            #pragma unroll
            for (int off = 8; off >= 1; off >>= 1) sum += __shfl_xor(sum, off);
            sw00[t] = ex / sum;
        }
    }
    __syncthreads();

    // ---------- Phase D: row-quad gather -> X rows (incl. row16 self half) ----------
    {
        const int q = q0;         // col quad: cols 4q..4q+3
        const int g = g0;         // 0..7 -> k in {g, g+8}
        const f32x4 rv4 = *(const f32x4*)&relv[q * 4];
        f32x4 pagg = {0.f, 0.f, 0.f, 0.f};

        if (g == 0) {   // hop-0 self row (row16, no swizzle) — data already in flight
            bf16x4 h0s;
            #pragma unroll
            for (int c = 0; c < 4; ++c) h0s[c] = (__bf16)(ev0q[c] * rv4[c]);
            *(bf16x4*)(Xb + 16 * 512 + q * 8) = h0s;
        }

        for (int kx = 0; kx < 2; ++kx) {
            const int k = g + kx * 8;
            const int swz = (k & 7) << 4;

            const f32x4 sv = load_rq<BT>(tab, se1[k], q);
            pagg += sw00[k] * sv;
            bf16x4 xs;
            xs[0] = (__bf16)(sv[0] * rv4[0]);
            xs[1] = (__bf16)(sv[1] * rv4[1]);
            xs[2] = (__bf16)(sv[2] * rv4[2]);
            xs[3] = (__bf16)(sv[3] * rv4[3]);
            *(bf16x4*)(Xb + ((k * 512 + q * 8) ^ swz)) = xs;

            i32x4 i0 = *(const i32x4*)&se2[k][0];
            i32x4 i1 = *(const i32x4*)&se2[k][4];
            i32x4 i2 = *(const i32x4*)&se2[k][8];
            i32x4 i3 = *(const i32x4*)&se2[k][12];
            f32x4 w0 = *(const f32x4*)&sw01[k][0];
            f32x4 w1 = *(const f32x4*)&sw01[k][4];
            f32x4 w2 = *(const f32x4*)&sw01[k][8];
            f32x4 w3 = *(const f32x4*)&sw01[k][12];

            f32x4 v0  = load_rq<BT>(tab, i0[0], q);
            f32x4 v1  = load_rq<BT>(tab, i0[1], q);
            f32x4 v2  = load_rq<BT>(tab, i0[2], q);
            f32x4 v3  = load_rq<BT>(tab, i0[3], q);
            f32x4 v4  = load_rq<BT>(tab, i1[0], q);
            f32x4 v5  = load_rq<BT>(tab, i1[1], q);
            f32x4 v6  = load_rq<BT>(tab, i1[2], q);
            f32x4 v7  = load_rq<BT>(tab, i1[3], q);
            f32x4 v8  = load_rq<BT>(tab, i2[0], q);
            f32x4 v9  = load_rq<BT>(tab, i2[1], q);
            f32x4 v10 = load_rq<BT>(tab, i2[2], q);
            f32x4 v11 = load_rq<BT>(tab, i2[3], q);
            f32x4 v12 = load_rq<BT>(tab, i3[0], q);
            f32x4 v13 = load_rq<BT>(tab, i3[1], q);
            f32x4 v14 = load_rq<BT>(tab, i3[2], q);
            f32x4 v15 = load_rq<BT>(tab, i3[3], q);

            f32x4 s01 = w0[0] * v0;  s01 += w0[1] * v1;
            f32x4 s23 = w0[2] * v2;  s23 += w0[3] * v3;
            f32x4 s45 = w1[0] * v4;  s45 += w1[1] * v5;
            f32x4 s67 = w1[2] * v6;  s67 += w1[3] * v7;
            f32x4 s89 = w2[0] * v8;  s89 += w2[1] * v9;
            f32x4 sab = w2[2] * v10; sab += w2[3] * v11;
            f32x4 scd = w3[0] * v12; scd += w3[1] * v13;
            f32x4 sef = w3[2] * v14; sef += w3[3] * v15;
            s01 += s23; s45 += s67; s89 += sab; scd += sef;
            s01 += s45; s89 += scd;
            f32x4 acc = s01 + s89;

            bf16x4 xa;
            xa[0] = (__bf16)(acc[0] * rv4[0]);
            xa[1] = (__bf16)(acc[1] * rv4[1]);
            xa[2] = (__bf16)(acc[2] * rv4[2]);
            xa[3] = (__bf16)(acc[3] * rv4[3]);
            *(bf16x4*)(Xb + ((k * 512 + 256 + q * 8) ^ swz)) = xa;
        }
        scr4[g][q] = pagg;
    }
    __syncthreads();
    if (t < 32) {   // row16 agg half
        f32x4 s = scr4[0][t];
        #pragma unroll
        for (int g = 1; g < 8; ++g) s += scr4[g][t];
        const f32x4 rv4 = *(const f32x4*)&relv[t * 4];
        bf16x4 h0a;
        #pragma unroll
        for (int c = 0; c < 4; ++c) h0a[c] = (__bf16)(s[c] * rv4[c]);
        *(bf16x4*)(Xb + 16 * 512 + 256 + t * 8) = h0a;
    }
    __syncthreads();

    // ---------- Phase E: MFMA  P = X @ [Ws0;Wn0] ----------
    const int w = t >> 6, l = t & 63;
    f32x4 acc00 = {0.f, 0.f, 0.f, 0.f};
    f32x4 acc01 = {0.f, 0.f, 0.f, 0.f};
    f32x4 acc10 = {0.f, 0.f, 0.f, 0.f};
    f32x4 acc11 = {0.f, 0.f, 0.f, 0.f};
    {
        const int row0 = l & 15;
        const int kb   = (l >> 4) * 16;
        const int sw0  = (row0 & 7) << 4;
        #pragma unroll
        for (int s = 0; s < 8; ++s) {
            bf16x8 a0 = *(const bf16x8*)(Xb + ((row0 * 512 + s * 64 + kb) ^ sw0));
            bf16x8 a1 = *(const bf16x8*)(Xb + (16 * 512 + s * 64 + kb));
            bf16x8 b0 = *(const bf16x8*)(packW + ((s * 8 + 2 * w) * 64 + l) * 8);
            bf16x8 b1 = *(const bf16x8*)(packW + ((s * 8 + 2 * w + 1) * 64 + l) * 8);
            acc00 = __builtin_amdgcn_mfma_f32_16x16x32_bf16(a0, b0, acc00, 0, 0, 0);
            acc01 = __builtin_amdgcn_mfma_f32_16x16x32_bf16(a0, b1, acc01, 0, 0, 0);
            acc10 = __builtin_amdgcn_mfma_f32_16x16x32_bf16(a1, b0, acc10, 0, 0, 0);
            acc11 = __builtin_amdgcn_mfma_f32_16x16x32_bf16(a1, b1, acc11, 0, 0, 0);
        }
    }
    __syncthreads();   // all reads of X done -> safe to overlay Y

    // ---------- zero Y tile (rows 0..15 of Xb) ----------
    {
        f32x4 z = {0.f, 0.f, 0.f, 0.f};
        *(f32x4*)(Xb + t * 32)      = z;
        *(f32x4*)(Xb + t * 32 + 16) = z;
    }
    __syncthreads();

    // ---------- post-E: relu + w00-agg -> Y row 0 ([v0 | aggf]) ----------
    {
        const int rbase = (l >> 4) * 4;
        float s0 = 0.f, s1 = 0.f;
        #pragma unroll
        for (int r = 0; r < 4; ++r) {
            float wk = sw00[rbase + r];
            s0 = fmaf(wk, fmaxf(acc00[r], 0.f), s0);
            s1 = fmaf(wk, fmaxf(acc01[r], 0.f), s1);
        }
        s0 += __shfl_xor(s0, 16); s0 += __shfl_xor(s0, 32);
        s1 += __shfl_xor(s1, 16); s1 += __shfl_xor(s1, 32);
        if (l < 16) {   // Y row 0: swizzle (0&7)<<4 == 0
            int c0 = 2 * w * 16 + l, c1 = c0 + 16;
            *(__bf16*)(Xb + c0 * 2)         = (__bf16)fmaxf(acc10[0], 0.f);
            *(__bf16*)(Xb + c1 * 2)         = (__bf16)fmaxf(acc11[0], 0.f);
            *(__bf16*)(Xb + (128 + c0) * 2) = (__bf16)s0;
            *(__bf16*)(Xb + (128 + c1) * 2) = (__bf16)s1;
        }
    }
    __syncthreads();

    // ---------- Phase H: out row = Y @ [Ws1;Wn1] (stuffed M-tile) ----------
    float* hout = (float*)scr4;
    {
        f32x4 h0 = {0.f, 0.f, 0.f, 0.f};
        f32x4 h1 = {0.f, 0.f, 0.f, 0.f};
        const int row0 = l & 15;
        const int kb   = (l >> 4) * 16;
        const int sw0  = (row0 & 7) << 4;
        const __bf16* packW1 = packW + 32768;
        #pragma unroll
        for (int s = 0; s < 8; ++s) {
            bf16x8 a   = *(const bf16x8*)(Xb + ((row0 * 512 + s * 64 + kb) ^ sw0));
            bf16x8 b0  = *(const bf16x8*)(packW1 + ((s * 8 + 2 * w) * 64 + l) * 8);
            bf16x8 b1  = *(const bf16x8*)(packW1 + ((s * 8 + 2 * w + 1) * 64 + l) * 8);
            h0 = __builtin_amdgcn_mfma_f32_16x16x32_bf16(a, b0, h0, 0, 0, 0);
            h1 = __builtin_amdgcn_mfma_f32_16x16x32_bf16(a, b1, h1, 0, 0, 0);
        }
        if (l < 16) {   // D row 0 = reg 0 of lanes l<16
            int c0 = 2 * w * 16 + l, c1 = c0 + 16;
            hout[c0] = h0[0];
            hout[c1] = h1[0];
        }
    }
    __syncthreads();

    // ---------- normalize + write ----------
    if (t < 64) {
        float a  = hout[t * 2];
        float bb = hout[t * 2 + 1];
        float sq = a * a + bb * bb;
        #pragma unroll
        for (int off = 1; off < 64; off <<= 1) sq += __shfl_xor(sq, off);
        float inv = 1.f / fmaxf(sqrtf(sq), 1e-12f);
        out[b * EMB + t * 2]     = a * inv;
        out[b * EMB + t * 2 + 1] = bb * inv;
    }
}

extern "C" void kernel_launch(void* const* d_in, const int* in_sizes, int n_in,
                              void* d_out, int out_size, void* d_ws, size_t ws_size,
                              hipStream_t stream) {
    (void)n_in; (void)out_size;
    const int*   node      = (const int*)d_in[0];
    const int*   relation  = (const int*)d_in[1];
    const int*   adj_node  = (const int*)d_in[2];
    const int*   adj_rela  = (const int*)d_in[3];
    const int*   node_type = (const int*)d_in[4];
    const float* node_emb  = (const float*)d_in[5];
    const float* rela_emb  = (const float*)d_in[6];
    const float* type_w    = (const float*)d_in[7];
    const float* Ws0       = (const float*)d_in[8];
    const float* Wn0       = (const float*)d_in[9];
    const float* Ws1       = (const float*)d_in[10];
    const float* Wn1       = (const float*)d_in[11];
    float* out = (float*)d_out;
    const int B     = in_sizes[0];
    const int nnode = in_sizes[5] / EMB;

    __bf16* packW = (__bf16*)d_ws;                          // 128 KB (W0 + W1 frags)
    float*  rsimg = (float*)((char*)d_ws + 131072);         // 1 KB
    __bf16* tabbf = (__bf16*)((char*)d_ws + 132096);        // nnode*256 B
    const size_t need = 132096 + (size_t)nnode * EMB * 2;

    if (ws_size >= need) {
        const int n4 = nnode * EMB / 4;
        const int prep_grid = 33 + (n4 + 255) / 256;
        prep_all_kernel<<<prep_grid, 256, 0, stream>>>(Ws0, Wn0, Ws1, Wn1, rela_emb,
                                                       node_emb, packW, rsimg, tabbf, n4);
        gnn_kernel<true><<<B, 256, 0, stream>>>(node, relation, adj_node, adj_rela,
                                                node_type, (const void*)tabbf, rela_emb,
                                                type_w, packW, rsimg, out);
    } else {
        prep_all_kernel<<<33, 256, 0, stream>>>(Ws0, Wn0, Ws1, Wn1, rela_emb,
                                                node_emb, packW, rsimg, tabbf, 0);
        gnn_kernel<false><<<B, 256, 0, stream>>>(node, relation, adj_node, adj_rela,
                                                 node_type, (const void*)node_emb, rela_emb,
                                                 type_w, packW, rsimg, out);
    }
}